// Round 11
// baseline (96.371 us; speedup 1.0000x reference)
//
#include <hip/hip_runtime.h>
#include <hip/hip_fp16.h>

// QDPPMixer, R11: MFMA Gram. R8/R10 falsified concurrency models (2x MLP, 2x
// occupancy: both neutral) — plateau may be VALU-issue-side (~27% issue eff).
// This round holds the R7 gather pattern EXACTLY (lane l loads 16B of row
// l&15: 16 lines/instr, 4-way shared) and halves VALU: one
// v_mfma_f32_16x16x32_f16 with A==B computes D = R*R^T for 16 staged rows =
// TWO elements' 8x8 Grams (diag blocks) per instruction; 8 MFMAs replace
// 288 dot2/DPP wave-instrs per 16 elements. D goes through a per-wave LDS
// block (stride 260 dwords: worst 2-way bank conflict = free) to land each
// element's Gram in its quad for the replicated epilogue (R5 algebra:
// det(M) = det(Atil)/prod(g_ii), no normalize).

constexpr int   NA         = 8;
constexpr float Q_MIN      = -10.0f;
constexpr float Q_MAX      = 10.0f;
constexpr float NOISE_COEF = 0.1f;
constexpr float EPS        = 1e-8f;

typedef _Float16 f16x8 __attribute__((ext_vector_type(8)));
typedef float    f32x4 __attribute__((ext_vector_type(4)));

// ---- convert W (8000x32 fp32) -> fp16, 4 floats/thread ----
__global__ __launch_bounds__(256) void convert_kernel(
    const float* __restrict__ W, __half* __restrict__ W16, int n4)
{
    int t = blockIdx.x * blockDim.x + threadIdx.x;
    if (t >= n4) return;
    float4 v = reinterpret_cast<const float4*>(W)[t];
    ushort4 h;
    h.x = __half_as_ushort(__float2half(v.x));
    h.y = __half_as_ushort(__float2half(v.y));
    h.z = __half_as_ushort(__float2half(v.z));
    h.w = __half_as_ushort(__float2half(v.w));
    reinterpret_cast<ushort4*>(W16)[t] = h;
}

__global__ __launch_bounds__(256, 4) void qdpp_kernel(
    const float* __restrict__ agent_qs,
    const int*   __restrict__ states,
    const int*   __restrict__ actions,
    const float* __restrict__ noise,
    const __half* __restrict__ W16,   // (8000, 32) fp16, rows 64B = 1 line
    float*       __restrict__ out,
    int bs)
{
    // per-wave LDS scratch: 8 p-blocks x 260 dwords (padded 16x16 f32)
    __shared__ __align__(16) float lds[4 * 8 * 260];

    int lane = threadIdx.x & 63;
    int wave = threadIdx.x >> 6;
    int e_base = (blockIdx.x * 4 + wave) * 16;   // 16 elements per wave

    // MFMA A-operand mapping for 16x16x32 f16: lane holds A[m=lane&15][k=8*(lane>>4)+j]
    // row m<8 -> element 2p (agent m); m>=8 -> element 2p+1 (agent m-8)
    int a  = lane & 7;          // agent
    int b8 = (lane >> 3) & 1;   // which element of the pair
    int c4 = lane >> 4;         // 16B chunk of the 64B row

    // ---- offsets + gathers: 8 loads, each = 16 lines, 4-way lane-shared ----
    uint4 raw[8];
    #pragma unroll
    for (int p = 0; p < 8; p++) {
        int ep = e_base + 2 * p + b8;
        int s  = states [ep * NA + a];
        int ac = actions[ep * NA + a];
        int off = (s * 10 + ac + 1000 * a) * 32 + 8 * c4;   // halves
        raw[p] = *reinterpret_cast<const uint4*>(W16 + off);
    }

    // ---- 8 MFMAs: D = R*R^T (A==B) -> two 8x8 Grams per instr; stash in LDS ----
    float* ldsw = lds + wave * 2080;
    int wr = (lane & 15) * 16 + (lane >> 4) * 4;   // store D[r][c] at [c*16+r]
    #pragma unroll
    for (int p = 0; p < 8; p++) {
        f32x4 acc = {0.0f, 0.0f, 0.0f, 0.0f};
        f16x8 f = __builtin_bit_cast(f16x8, raw[p]);
        acc = __builtin_amdgcn_mfma_f32_16x16x32_f16(f, f, acc, 0, 0, 0);
        *reinterpret_cast<f32x4*>(ldsw + p * 260 + wr) = acc;
    }

    __syncthreads();   // orders LDS write->read (within-wave, but be safe)

    // ---- per-quad epilogue (replicated x4 lanes, as R7) ----
    int q  = lane >> 2;          // quad = element within wave
    int e  = e_base + q;
    size_t base = (size_t)e * NA;
    int pq = q >> 1, bq = q & 1;
    const float* rb = ldsw + pq * 260 + 136 * bq;  // 136 = 8*16 + 8 (diag block)

    float4 qa = *reinterpret_cast<const float4*>(agent_qs + base);
    float4 qb = *reinterpret_cast<const float4*>(agent_qs + base + 4);
    float4 n0 = *reinterpret_cast<const float4*>(noise + base);
    float4 n1 = *reinterpret_cast<const float4*>(noise + base + 4);
    float nz[8] = {n0.x, n0.y, n0.z, n0.w, n1.x, n1.y, n1.z, n1.w};

    // read column j of this element's Gram (contiguous in LDS), build Atil
    float m[8][8];
    float pgii = 1.0f;
    #pragma unroll
    for (int j = 0; j < 8; j++) {
        float4 lo = *reinterpret_cast<const float4*>(rb + j * 16);
        float4 hi = *reinterpret_cast<const float4*>(rb + j * 16 + 4);
        float v[8] = {lo.x, lo.y, lo.z, lo.w, hi.x, hi.y, hi.z, hi.w};
        #pragma unroll
        for (int i = 0; i < 8; i++)
            m[i][j] = fmaxf(v[i], 0.0f);
        float gjj = v[j];
        pgii *= gjj;
        m[j][j] = gjj * fmaf(NOISE_COEF, nz[j], 1.0f + EPS);
    }

    float qsum = fminf(fmaxf(qa.x, Q_MIN), Q_MAX) + fminf(fmaxf(qa.y, Q_MIN), Q_MAX)
               + fminf(fmaxf(qa.z, Q_MIN), Q_MAX) + fminf(fmaxf(qa.w, Q_MIN), Q_MAX)
               + fminf(fmaxf(qb.x, Q_MIN), Q_MAX) + fminf(fmaxf(qb.y, Q_MIN), Q_MAX)
               + fminf(fmaxf(qb.z, Q_MIN), Q_MAX) + fminf(fmaxf(qb.w, Q_MIN), Q_MAX);

    // ---- det via unrolled no-pivot LU (diag-dominant in practice) ----
    float det = 1.0f;
    #pragma unroll
    for (int k = 0; k < 8; k++) {
        float p = m[k][k];
        det *= p;
        float ip = __builtin_amdgcn_rcpf(p);
        #pragma unroll
        for (int i = k + 1; i < 8; i++) {
            float f = m[i][k] * ip;
            #pragma unroll
            for (int j = k + 1; j < 8; j++)
                m[i][j] = fmaf(-f, m[k][j], m[i][j]);
        }
    }

    // det(M) = det(Atil)/prod(g_ii); out = qsum + log(det(M) + 1e-8)
    float detM = det * __builtin_amdgcn_rcpf(pgii);
    if ((lane & 3) == 0)
        out[e] = qsum + __logf(detM + EPS);
}

extern "C" void kernel_launch(void* const* d_in, const int* in_sizes, int n_in,
                              void* d_out, int out_size, void* d_ws, size_t ws_size,
                              hipStream_t stream) {
    const float* agent_qs = (const float*)d_in[0];
    const int*   states   = (const int*)d_in[1];
    const int*   actions  = (const int*)d_in[2];
    const float* noise    = (const float*)d_in[3];
    const float* W        = (const float*)d_in[4];
    float*       out      = (float*)d_out;
    __half*      W16      = (__half*)d_ws;          // 256000 halves = 512 KB

    int wn = in_sizes[4];             // 256000 floats
    int n4 = wn / 4;
    convert_kernel<<<(n4 + 255) / 256, 256, 0, stream>>>(W, W16, n4);

    int bs = in_sizes[0] / NA;            // 262144
    const int block = 256;                // 4 waves, 16 elements/wave
    long long total = (long long)bs * 4;  // 4 lanes per element
    int grid = (int)((total + block - 1) / block);   // 4096 WGs
    qdpp_kernel<<<grid, block, 0, stream>>>(agent_qs, states, actions, noise, W16, out, bs);
}